// Round 11
// baseline (15456.865 us; speedup 1.0000x reference)
//
#include <hip/hip_runtime.h>

// GRU  B=128, T=1024, IN=256, H=512, OUT=1  (all fp32)
//
// v11: designed to FIT the 128-VGPR budget the allocator insists on
// (v9/v10 proof: 148 pinned floats at VGPR_Count=128 -> ~80 spilled values,
// VALU issue 3x useful FMA). New geometry:
//   1024-thr wgs (16 waves, launch_bounds(1024,4) = native 128-reg point).
//   16 groups x 16 wgs (g=bid&15 -> whole group on one XCD under round-robin);
//   group owns 8 samples; wg owns 32 j. Thread (j in [0,32), ks in [0,32)):
//   W_hh 3x16 + W_ih 3x8 = 72 weight floats + 24 x-accs + addressing ~= 115.
//   Reduce = DPP row_shr x4 + row_bcast15 add (total at lane ks==31), zero
//   LDS/shfl. Per-sample fused h-phase/reduce/gate caps live regs.
//   h staged per step into chunk-padded LDS (16f->20f, 4-way b128 reads).
//   Write-back: wave0, global_store_dwordx2, 4 samples' rows per instr.
//   Sync (v10-proven): wave0-only poll of 16 monotonic sc0/sc1 flags,
//   s_sleep backoff, 1<<21 guard; barrier P hands off to the other waves.

#define B_    128
#define T_    1024
#define IN_   256
#define H_    512
#define NG    16
#define WPG   16
#define SGRP  8
#define JT    32
#define NT    1024
#define RW    640                 // 32 chunks x 20 floats (padded)
#define LDS_DYN (SGRP*RW*4)       // 20,480 B h tile (+ static hnew_sh)

__device__ __forceinline__ float sig_(float v){ return 1.0f/(1.0f + __expf(-v)); }
__device__ __forceinline__ float tanh_(float v){
  float e = __expf(2.0f*v);       // tanh = 1 - 2/(e^{2x}+1); inf-safe
  return 1.0f - 2.0f/(e + 1.0f);
}

// IF-coherent (cache-bypassing) ops. Data operands <=64 bit only.
#define CLOAD4(dst, p)  asm volatile("global_load_dwordx4 %0, %1, off sc0 sc1" : "=v"(dst) : "v"(p) : "memory")
#define CLOAD1(dst, p)  asm volatile("global_load_dword %0, %1, off sc0 sc1"   : "=v"(dst) : "v"(p) : "memory")
#define CSTORE1(p, v)   asm volatile("global_store_dword %0, %1, off sc0 sc1"  :: "v"(p), "v"(v) : "memory")
#define CSTORE2(p, v)   asm volatile("global_store_dwordx2 %0, %1, off sc0 sc1" :: "v"(p), "v"(v) : "memory")
#define VWAIT0()        do{ asm volatile("s_waitcnt vmcnt(0)" ::: "memory"); __builtin_amdgcn_sched_barrier(0); }while(0)

#define FMA4A(acc, v, warr, base) do{           \
  acc = fmaf((v).x, warr[(base)+0], acc);       \
  acc = fmaf((v).y, warr[(base)+1], acc);       \
  acc = fmaf((v).z, warr[(base)+2], acc);       \
  acc = fmaf((v).w, warr[(base)+3], acc); }while(0)

// 32-lane sum entirely on the VALU pipe: row_shr prefix within 16-lane rows
// (row sums at lanes 15/31/47/63), then row_bcast15 (0x142) adds lane15 into
// lanes 16-31 (and 47 into 48-63) -> full 32-sum at lanes 31 and 63 (ks==31).
__device__ __forceinline__ float rowsum32(float v){
  float s = v; int t_;
  t_ = __builtin_amdgcn_update_dpp(0, __float_as_int(s), 0x111, 0xF, 0xF, true); s += __int_as_float(t_);
  t_ = __builtin_amdgcn_update_dpp(0, __float_as_int(s), 0x112, 0xF, 0xF, true); s += __int_as_float(t_);
  t_ = __builtin_amdgcn_update_dpp(0, __float_as_int(s), 0x114, 0xF, 0xF, true); s += __int_as_float(t_);
  t_ = __builtin_amdgcn_update_dpp(0, __float_as_int(s), 0x118, 0xF, 0xF, true); s += __int_as_float(t_);
  t_ = __builtin_amdgcn_update_dpp(0, __float_as_int(s), 0x142, 0xF, 0xF, true); s += __int_as_float(t_);
  return s;
}

// poll all 16 group flags >= target (wave0 only). s_sleep backoff;
// guard 1<<21 (~0.3s) => spurious trips impossible.
__device__ __forceinline__ int poll_group(const int* fbase, int lane, int target){
  const int* fp = fbase + (lane & (WPG-1));
  int guard = 0;
  for (;;){
    int fv;
    CLOAD1(fv, fp);
    asm volatile("s_waitcnt vmcnt(0)" ::: "memory");
    if (__all(fv >= target)) return 0;
    __builtin_amdgcn_s_sleep(4);
    if (++guard > (1<<21)) return 1;
  }
}

__global__ void __launch_bounds__(NT, 4)
rnn_persist(const float* __restrict__ x, const float* __restrict__ W_ih,
            const float* __restrict__ W_hh, const float* __restrict__ bias,
            const float* __restrict__ bias_n, float* __restrict__ h_buf,
            int* __restrict__ flags)
{
  extern __shared__ float HT[];                      // [8][RW]
  __shared__ __align__(16) float hnew_sh[SGRP][JT];  // [8][32]

  const int bid = (int)blockIdx.x;
  const int g   = bid & (NG-1);
  const int w   = bid >> 4;            // wg within group [0,16)
  const int tid = (int)threadIdx.x;
  const int j   = tid >> 5;            // [0,32)
  const int ks  = tid & 31;            // k-group [0,32)
  const int jg  = w*JT + j;
  const int b0  = g*SGRP;
  const int lane = tid & 63;

  // ---- weights into registers: W_hh k-chunk [16ks,16ks+16), W_ih [8ks,+8) ----
  float wr[16], wz[16], wn[16];
#pragma unroll
  for (int q=0;q<4;q++){
    *(float4*)&wr[4*q] = *(const float4*)&W_hh[((size_t)0*H_ + jg)*H_ + ks*16 + 4*q];
    *(float4*)&wz[4*q] = *(const float4*)&W_hh[((size_t)1*H_ + jg)*H_ + ks*16 + 4*q];
    *(float4*)&wn[4*q] = *(const float4*)&W_hh[((size_t)2*H_ + jg)*H_ + ks*16 + 4*q];
  }
  float wxr[8], wxz[8], wxn[8];
#pragma unroll
  for (int q=0;q<2;q++){
    *(float4*)&wxr[4*q] = *(const float4*)&W_ih[((size_t)0*H_ + jg)*IN_ + ks*8 + 4*q];
    *(float4*)&wxz[4*q] = *(const float4*)&W_ih[((size_t)1*H_ + jg)*IN_ + ks*8 + 4*q];
    *(float4*)&wxn[4*q] = *(const float4*)&W_ih[((size_t)2*H_ + jg)*IN_ + ks*8 + 4*q];
  }
  float br = bias[jg], bz = bias[H_+jg], bni = bias[2*H_+jg], bnh = bias_n[jg];
  // pin: loads cannot be sunk back into the loop (round-2 failure mode)
#pragma unroll
  for (int i=0;i<16;i++) asm volatile("" : "+v"(wr[i]), "+v"(wz[i]), "+v"(wn[i]));
#pragma unroll
  for (int i=0;i<8;i++)  asm volatile("" : "+v"(wxr[i]), "+v"(wxz[i]), "+v"(wxn[i]));
  asm volatile("" : "+v"(br), "+v"(bz), "+v"(bni), "+v"(bnh));

  float* const hb0 = h_buf;
  float* const hb1 = h_buf + (size_t)B_*H_;
  int dead = 0;

  for (int t=0; t<T_; ++t){
    const float* hc  = (t & 1) ? hb1 : hb0;
    float*       hnx = (t & 1) ? hb0 : hb1;

    // ---- x-phase (flag-independent; hides producer lag + HBM latency) ----
    float accR[8], accZ[8], accNI[8];
#pragma unroll
    for (int m=0;m<8;m++){
      const float* xr = x + ((size_t)(b0+m)*T_ + (size_t)t)*IN_ + ks*8;
      const float4 x0 = *(const float4*)(xr);
      const float4 x1 = *(const float4*)(xr+4);
      float aR=0.f, aZ=0.f, aNI=0.f;
      FMA4A(aR, x0, wxr, 0); FMA4A(aR, x1, wxr, 4);
      FMA4A(aZ, x0, wxz, 0); FMA4A(aZ, x1, wxz, 4);
      FMA4A(aNI,x0, wxn, 0); FMA4A(aNI,x1, wxn, 4);
      accR[m]=aR; accZ[m]=aZ; accNI[m]=aNI;
    }

    // ---- wave0 polls for h^t; other waves wait at barrier P ----
    if (tid < 64 && t > 0 && !dead) dead = poll_group(flags + g*WPG, lane, t);
    __syncthreads();                   // P: h^t globally visible

    // ---- stage 8x512 h tile into chunk-padded LDS (1 float4/thread) ----
    {
      const int ss = tid >> 7, cq = tid & 127;     // cq = float4 index in row
      const float* src = hc + (size_t)(b0+ss)*H_ + cq*4;
      float4 v0;
      CLOAD4(v0, src);
      VWAIT0();
      *(float4*)&HT[ss*RW + (cq>>2)*20 + (cq&3)*4] = v0;
    }
    __syncthreads();                   // B: HT(t) complete

    // ---- h-phase, fused per sample: FMA -> rowsum32 -> gates ----
#pragma unroll
    for (int m=0;m<8;m++){
      const float* p = HT + m*RW + ks*20;
      const float4 a0 = *(const float4*)(p);
      const float4 a1 = *(const float4*)(p+4);
      const float4 a2 = *(const float4*)(p+8);
      const float4 a3 = *(const float4*)(p+12);
      float aR = accR[m], aZ = accZ[m], aNH = 0.f;
      FMA4A(aR, a0, wr, 0);  FMA4A(aR, a1, wr, 4);  FMA4A(aR, a2, wr, 8);  FMA4A(aR, a3, wr, 12);
      FMA4A(aZ, a0, wz, 0);  FMA4A(aZ, a1, wz, 4);  FMA4A(aZ, a2, wz, 8);  FMA4A(aZ, a3, wz, 12);
      FMA4A(aNH,a0, wn, 0);  FMA4A(aNH,a1, wn, 4);  FMA4A(aNH,a2, wn, 8);  FMA4A(aNH,a3, wn, 12);
      aR  = rowsum32(aR);
      aZ  = rowsum32(aZ);
      aNH = rowsum32(aNH);
      const float aNI = rowsum32(accNI[m]);
      if (ks == 31){                   // lanes 31/63 hold the 32-lane totals
        const float h_old = HT[m*RW + (jg>>4)*20 + (jg&15)];
        const float r = sig_(aR + br);
        const float z = sig_(aZ + bz);
        const float n = tanh_(aNI + bni + r*(aNH + bnh));
        hnew_sh[m][j] = (1.0f - z)*n + z*h_old;
      }
    }
    __syncthreads();                   // A: hnew_sh complete; HT reads done

    // ---- wave 0: coalesced write-back (dwordx2; 4 sample-rows/instr) ----
    if (tid < 64){
#pragma unroll
      for (int k=0;k<2;k++){
        const int e    = tid + 64*k;   // [0,128): 8 samples x 16 float2
        const int ss2  = e >> 4;
        const int col2 = (e & 15)*2;
        const double hv = *(const double*)&hnew_sh[ss2][col2];
        CSTORE2(hnx + (size_t)(b0+ss2)*H_ + w*JT + col2, hv);
      }
      asm volatile("s_waitcnt vmcnt(0)" ::: "memory");   // drain before flag
    }
    if (tid == 0){
      int* fp = &flags[g*WPG + w];
      const int fv = t + 1;
      CSTORE1(fp, fv);
    }
    // waves 1-15 run ahead into x-phase(t+1); barrier P orders them.
  }
}

__global__ void head_k(const float* __restrict__ h, const float* __restrict__ W_out,
                       const float* __restrict__ b_out, float* __restrict__ out)
{
  const int b = (int)blockIdx.x;       // 128 blocks, one sample each
  const int l = (int)threadIdx.x;      // 64 lanes
  const float* hp = h + (size_t)b*H_ + l*8;
  const float* wp = W_out + l*8;
  float a = 0.f;
#pragma unroll
  for (int q=0;q<2;q++){
    const float4 hv = *(const float4*)(hp + 4*q);
    const float4 wv = *(const float4*)(wp + 4*q);
    a = fmaf(hv.x, wv.x, a); a = fmaf(hv.y, wv.y, a);
    a = fmaf(hv.z, wv.z, a); a = fmaf(hv.w, wv.w, a);
  }
#pragma unroll
  for (int m=1;m<64;m<<=1) a += __shfl_xor(a, m, 64);
  if (l == 0) out[b] = sig_(a + b_out[0]);
}

extern "C" void kernel_launch(void* const* d_in, const int* in_sizes, int n_in,
                              void* d_out, int out_size, void* d_ws, size_t ws_size,
                              hipStream_t stream)
{
  const float* x    = (const float*)d_in[0];
  const float* Wih  = (const float*)d_in[1];
  const float* Whh  = (const float*)d_in[2];
  const float* bias = (const float*)d_in[3];
  const float* bn   = (const float*)d_in[4];
  const float* Wout = (const float*)d_in[5];
  const float* bout = (const float*)d_in[6];
  float* out   = (float*)d_out;
  float* h_buf = (float*)d_ws;                                         // 512 KB
  int* flags   = (int*)((char*)d_ws + (size_t)2*B_*H_*sizeof(float));  // 1 KB used

  // zero h0 + flags every launch (captured into the graph)
  (void)hipMemsetAsync(d_ws, 0, (size_t)2*B_*H_*sizeof(float) + 4096, stream);

  (void)hipFuncSetAttribute((const void*)rnn_persist,
                            hipFuncAttributeMaxDynamicSharedMemorySize, LDS_DYN);

  void* args[7];
  args[0]=(void*)&x;    args[1]=(void*)&Wih;  args[2]=(void*)&Whh; args[3]=(void*)&bias;
  args[4]=(void*)&bn;   args[5]=(void*)&h_buf; args[6]=(void*)&flags;
  hipError_t e = hipLaunchCooperativeKernel((const void*)rnn_persist,
                                            dim3(256), dim3(NT), args, LDS_DYN, stream);
  if (e != hipSuccess){
    (void)hipGetLastError();
    rnn_persist<<<dim3(256), dim3(NT), LDS_DYN, stream>>>(x, Wih, Whh, bias, bn, h_buf, flags);
  }
  // T_ even -> final h in hb0; kernel boundary makes h_buf coherent for head_k
  head_k<<<dim3(128), dim3(64), 0, stream>>>(h_buf, Wout, bout, out);
}

// Round 12
// 12263.927 us; speedup vs baseline: 1.2604x; 1.2604x over previous
//
#include <hip/hip_runtime.h>

// GRU  B=128, T=1024, IN=256, H=512, OUT=1  (all fp32)
//
// v12 = v10's proven sync skeleton + NON-DUPLICATED weight layout that fits
// the 128-VGPR budget the allocator enforces (proven r2/r9/r10/r11; asm "pins"
// cannot force residency -- the allocator spills after the asm).
//   v9/v10 layout (j16,sg2,ks16) duplicated every weight 2x -> 144 f/thread
//   -> ~20-40 values re-spilled per step. v12 layout (j in [0,16), ks in
//   [0,32)) covers all 512 threads distinctly -> 72 weight floats/thread
//   (wr/wz/wn[16] + wxr/wxz/wxn[8]) + 4 biases. Peak live ~140; any spilled
//   x-accumulators are 2-use/step (cheap, L1-local) vs weights 16-use/step.
//   Reduce across the 32 ks-lanes: DPP row_shr x4 + row_bcast15 (rowsum32,
//   v11-validated); totals at ks==31 (lanes 31/63).
// Unchanged from v10 (12.5 ms, passed):
//   256 wgs x 512 thr persistent; 8 groups x 32 wgs; group = 16 samples;
//   h staged per step into chunk-padded LDS (16f->20f); wave0-only sc0/sc1
//   flag poll + s_sleep backoff + 1<<21 guard; barrier P hand-off; wave0
//   coalesced write-back; separate head kernel.

#define B_    128
#define T_    1024
#define IN_   256
#define H_    512
#define NG    8
#define WPG   32
#define SGRP  16
#define JT    16
#define NT    512
#define RW    640                 // 32 chunks x 20 floats (padded)
#define LDS_DYN (SGRP*RW*4)       // 40,960 B h tile (+ static hnew_sh)

__device__ __forceinline__ float sig_(float v){ return 1.0f/(1.0f + __expf(-v)); }
__device__ __forceinline__ float tanh_(float v){
  float e = __expf(2.0f*v);       // tanh = 1 - 2/(e^{2x}+1); inf-safe
  return 1.0f - 2.0f/(e + 1.0f);
}

// IF-coherent (cache-bypassing) ops. Data operands <=64 bit only.
#define CLOAD4(dst, p)  asm volatile("global_load_dwordx4 %0, %1, off sc0 sc1" : "=v"(dst) : "v"(p) : "memory")
#define CLOAD1(dst, p)  asm volatile("global_load_dword %0, %1, off sc0 sc1"   : "=v"(dst) : "v"(p) : "memory")
#define CSTORE1(p, v)   asm volatile("global_store_dword %0, %1, off sc0 sc1"  :: "v"(p), "v"(v) : "memory")
#define VWAIT0()        do{ asm volatile("s_waitcnt vmcnt(0)" ::: "memory"); __builtin_amdgcn_sched_barrier(0); }while(0)

#define FMA4A(acc, v, warr, base) do{           \
  acc = fmaf((v).x, warr[(base)+0], acc);       \
  acc = fmaf((v).y, warr[(base)+1], acc);       \
  acc = fmaf((v).z, warr[(base)+2], acc);       \
  acc = fmaf((v).w, warr[(base)+3], acc); }while(0)

// 32-lane sum on the VALU pipe (v11-validated): row_shr prefix within 16-lane
// rows, then row_bcast15 adds lane15 into 16-31 (and 47 into 48-63); full
// 32-lane totals land at lanes 31 and 63 (ks==31).
__device__ __forceinline__ float rowsum32(float v){
  float s = v; int t_;
  t_ = __builtin_amdgcn_update_dpp(0, __float_as_int(s), 0x111, 0xF, 0xF, true); s += __int_as_float(t_);
  t_ = __builtin_amdgcn_update_dpp(0, __float_as_int(s), 0x112, 0xF, 0xF, true); s += __int_as_float(t_);
  t_ = __builtin_amdgcn_update_dpp(0, __float_as_int(s), 0x114, 0xF, 0xF, true); s += __int_as_float(t_);
  t_ = __builtin_amdgcn_update_dpp(0, __float_as_int(s), 0x118, 0xF, 0xF, true); s += __int_as_float(t_);
  t_ = __builtin_amdgcn_update_dpp(0, __float_as_int(s), 0x142, 0xF, 0xF, true); s += __int_as_float(t_);
  return s;
}

// poll all 32 group flags >= target (wave0 only). s_sleep backoff;
// guard 1<<21 (~0.3s) => spurious trips impossible.
__device__ __forceinline__ int poll_group(const int* fbase, int lane, int target){
  const int* fp = fbase + (lane & 31);
  int guard = 0;
  for (;;){
    int fv;
    CLOAD1(fv, fp);
    asm volatile("s_waitcnt vmcnt(0)" ::: "memory");
    if (__all(fv >= target)) return 0;
    __builtin_amdgcn_s_sleep(4);
    if (++guard > (1<<21)) return 1;
  }
}

// stage 16x512 h tile into chunk-padded LDS (thread = (ss, chunk))
__device__ __forceinline__ void stage_h(const float* hc, float* HT, int tid, int b0){
  const int ss = tid >> 5, c = tid & 31;
  const float* src = hc + (size_t)(b0+ss)*H_ + c*16;
  float4 v0,v1,v2,v3;
  CLOAD4(v0, src); CLOAD4(v1, (src+4)); CLOAD4(v2, (src+8)); CLOAD4(v3, (src+12));
  VWAIT0();
  float* d = HT + ss*RW + c*20;
  *(float4*)(d)    = v0; *(float4*)(d+4)  = v1;
  *(float4*)(d+8)  = v2; *(float4*)(d+12) = v3;
}

__global__ void __launch_bounds__(NT, 2)
rnn_persist(const float* __restrict__ x, const float* __restrict__ W_ih,
            const float* __restrict__ W_hh, const float* __restrict__ bias,
            const float* __restrict__ bias_n, float* __restrict__ h_buf,
            int* __restrict__ flags)
{
  extern __shared__ float HT[];        // [16][RW]
  __shared__ float hnew_sh[SGRP][20];  // wg's new h slice: [sample][j] (padded)

  const int bid = (int)blockIdx.x;
  const int g   = bid & (NG-1);
  const int w   = bid >> 3;
  const int tid = (int)threadIdx.x;
  const int j   = tid >> 5;            // [0,16)
  const int ks  = tid & 31;            // [0,32)  -- NO duplication
  const int jg  = w*JT + j;
  const int b0  = g*SGRP;
  const int lane = tid & 63;

  // ---- weights into registers: W_hh k-chunk [16ks,+16), W_ih [8ks,+8) ----
  float wr[16], wz[16], wn[16];
#pragma unroll
  for (int q=0;q<4;q++){
    *(float4*)&wr[4*q] = *(const float4*)&W_hh[((size_t)0*H_ + jg)*H_ + ks*16 + 4*q];
    *(float4*)&wz[4*q] = *(const float4*)&W_hh[((size_t)1*H_ + jg)*H_ + ks*16 + 4*q];
    *(float4*)&wn[4*q] = *(const float4*)&W_hh[((size_t)2*H_ + jg)*H_ + ks*16 + 4*q];
  }
  float wxr[8], wxz[8], wxn[8];
#pragma unroll
  for (int q=0;q<2;q++){
    *(float4*)&wxr[4*q] = *(const float4*)&W_ih[((size_t)0*H_ + jg)*IN_ + ks*8 + 4*q];
    *(float4*)&wxz[4*q] = *(const float4*)&W_ih[((size_t)1*H_ + jg)*IN_ + ks*8 + 4*q];
    *(float4*)&wxn[4*q] = *(const float4*)&W_ih[((size_t)2*H_ + jg)*IN_ + ks*8 + 4*q];
  }
  const float br = bias[jg], bz = bias[H_+jg], bni = bias[2*H_+jg], bnh = bias_n[jg];

  float* const hb0 = h_buf;
  float* const hb1 = h_buf + (size_t)B_*H_;
  int dead = 0;

  for (int t=0; t<T_; ++t){
    const float* hc  = (t & 1) ? hb1 : hb0;
    float*       hnx = (t & 1) ? hb0 : hb1;

    // ---- x-phase (flag-independent; hides producer lag + HBM latency) ----
    float accR[SGRP], accZ[SGRP], accNI[SGRP];
#pragma unroll
    for (int m=0;m<SGRP;m++){
      const float* xr = x + ((size_t)(b0+m)*T_ + (size_t)t)*IN_ + ks*8;
      const float4 x0 = *(const float4*)(xr);
      const float4 x1 = *(const float4*)(xr+4);
      float aR=0.f, aZ=0.f, aNI=0.f;
      FMA4A(aR, x0, wxr, 0); FMA4A(aR, x1, wxr, 4);
      FMA4A(aZ, x0, wxz, 0); FMA4A(aZ, x1, wxz, 4);
      FMA4A(aNI,x0, wxn, 0); FMA4A(aNI,x1, wxn, 4);
      accR[m]=aR; accZ[m]=aZ;
      accNI[m]=rowsum32(aNI);          // finish NI's reduce now (fills poll wait)
    }

    // ---- wave0 polls for h^t; other waves wait at barrier P ----
    if (tid < 64 && t > 0 && !dead) dead = poll_group(flags + g*WPG, lane, t);
    __syncthreads();                   // P: h^t globally visible
    stage_h(hc, HT, tid, b0);
    __syncthreads();                   // B: HT(t) complete

    // ---- h-phase, fused per sample: FMA -> rowsum32 -> gates ----
#pragma unroll
    for (int m=0;m<SGRP;m++){
      const float* p = HT + m*RW + ks*20;
      const float4 a0 = *(const float4*)(p);
      const float4 a1 = *(const float4*)(p+4);
      const float4 a2 = *(const float4*)(p+8);
      const float4 a3 = *(const float4*)(p+12);
      float aR = accR[m], aZ = accZ[m], aNH = 0.f;
      FMA4A(aR, a0, wr, 0);  FMA4A(aR, a1, wr, 4);  FMA4A(aR, a2, wr, 8);  FMA4A(aR, a3, wr, 12);
      FMA4A(aZ, a0, wz, 0);  FMA4A(aZ, a1, wz, 4);  FMA4A(aZ, a2, wz, 8);  FMA4A(aZ, a3, wz, 12);
      FMA4A(aNH,a0, wn, 0);  FMA4A(aNH,a1, wn, 4);  FMA4A(aNH,a2, wn, 8);  FMA4A(aNH,a3, wn, 12);
      aR  = rowsum32(aR);
      aZ  = rowsum32(aZ);
      aNH = rowsum32(aNH);
      if (ks == 31){                   // lanes 31/63 hold the 32-lane totals
        const float h_old = HT[m*RW + (jg>>4)*20 + (jg&15)];
        const float r = sig_(aR + br);
        const float z = sig_(aZ + bz);
        const float n = tanh_(accNI[m] + bni + r*(aNH + bnh));
        hnew_sh[m][j] = (1.0f - z)*n + z*h_old;
      }
    }
    __syncthreads();                   // A: hnew_sh complete; HT reads done

    // ---- wave 0: coalesced write-back of the wg's 16x16 slice ----
    // lane stores dwords d = lane + 64k (k=0..3): per instruction the wave
    // covers 4 rows x 16 consecutive dwords = 4 full 64B sectors.
    if (tid < 64){
#pragma unroll
      for (int k=0;k<4;k++){
        const int d   = tid + 64*k;
        const int ss2 = d >> 4;        // sample [0,16)
        const int col = d & 15;        // j within slice
        const float hv = hnew_sh[ss2][col];
        CSTORE1(hnx + (size_t)(b0+ss2)*H_ + w*JT + col, hv);
      }
      asm volatile("s_waitcnt vmcnt(0)" ::: "memory");   // drain before flag
    }
    if (tid == 0){
      int* fp = &flags[g*WPG + w];
      const int fv = t + 1;
      CSTORE1(fp, fv);
    }
    // waves 1-7 run ahead into x-phase(t+1); barrier P orders them.
  }
}

__global__ void head_k(const float* __restrict__ h, const float* __restrict__ W_out,
                       const float* __restrict__ b_out, float* __restrict__ out)
{
  const int b = (int)blockIdx.x;       // 128 blocks, one sample each
  const int l = (int)threadIdx.x;      // 64 lanes
  const float* hp = h + (size_t)b*H_ + l*8;
  const float* wp = W_out + l*8;
  float a = 0.f;
#pragma unroll
  for (int q=0;q<2;q++){
    const float4 hv = *(const float4*)(hp + 4*q);
    const float4 wv = *(const float4*)(wp + 4*q);
    a = fmaf(hv.x, wv.x, a); a = fmaf(hv.y, wv.y, a);
    a = fmaf(hv.z, wv.z, a); a = fmaf(hv.w, wv.w, a);
  }
#pragma unroll
  for (int m=1;m<64;m<<=1) a += __shfl_xor(a, m, 64);
  if (l == 0) out[b] = sig_(a + b_out[0]);
}

extern "C" void kernel_launch(void* const* d_in, const int* in_sizes, int n_in,
                              void* d_out, int out_size, void* d_ws, size_t ws_size,
                              hipStream_t stream)
{
  const float* x    = (const float*)d_in[0];
  const float* Wih  = (const float*)d_in[1];
  const float* Whh  = (const float*)d_in[2];
  const float* bias = (const float*)d_in[3];
  const float* bn   = (const float*)d_in[4];
  const float* Wout = (const float*)d_in[5];
  const float* bout = (const float*)d_in[6];
  float* out   = (float*)d_out;
  float* h_buf = (float*)d_ws;                                         // 512 KB
  int* flags   = (int*)((char*)d_ws + (size_t)2*B_*H_*sizeof(float));  // 1 KB used

  // zero h0 + flags every launch (captured into the graph)
  (void)hipMemsetAsync(d_ws, 0, (size_t)2*B_*H_*sizeof(float) + 4096, stream);

  (void)hipFuncSetAttribute((const void*)rnn_persist,
                            hipFuncAttributeMaxDynamicSharedMemorySize, LDS_DYN);

  void* args[7];
  args[0]=(void*)&x;    args[1]=(void*)&Wih;  args[2]=(void*)&Whh; args[3]=(void*)&bias;
  args[4]=(void*)&bn;   args[5]=(void*)&h_buf; args[6]=(void*)&flags;
  hipError_t e = hipLaunchCooperativeKernel((const void*)rnn_persist,
                                            dim3(256), dim3(NT), args, LDS_DYN, stream);
  if (e != hipSuccess){
    (void)hipGetLastError();
    rnn_persist<<<dim3(256), dim3(NT), LDS_DYN, stream>>>(x, Wih, Whh, bias, bn, h_buf, flags);
  }
  // T_ even -> final h in hb0; kernel boundary makes h_buf coherent for head_k
  head_k<<<dim3(128), dim3(64), 0, stream>>>(h_buf, Wout, bout, out);
}

// Round 13
// 11838.618 us; speedup vs baseline: 1.3056x; 1.0359x over previous
//
#include <hip/hip_runtime.h>

// GRU  B=128, T=1024, IN=256, H=512, OUT=1  (all fp32)
//
// v13: split-bf16 MFMA. fp32 = bf16hi + bf16lo; W.u ~ Whi.uhi + Whi.ulo +
// Wlo.uhi (3 passes; dropped lo.lo ~ 3e-7 per dot). Virtual operand U[k],
// K=768 = x(256) ++ h(512), staged per step into LDS as bf16 hi/lo (row
// pitch 776). 4 gate row-sets: r,z (K=768), ni (x-only), nh (h-only).
// Per wg (512 thr, 8 waves): wave w8 owns K-chunks {3w8..3w8+2} (32-K each);
// 27 x mfma_f32_16x16x32_bf16 per wave per step. A=W frags: hi in 36 VGPRs
// (fits proven 128 budget), lo pre-swizzled in LDS. Layouts: A row=lane&15,
// k=8*(lane>>4)+i; B col=lane&15 same k; C/D col=lane&15 row=4*(lane>>4)+i
// (m89-verified). Cross-wave combine: ds_add_f32 into [4][16][17] LDS buf.
// Gate phase: 256 thr -> hnew packed (hi<<16|lo) u32 -> coalesced store.
// Sync = v12-proven: wave0-only sc0/sc1 flag poll, s_sleep backoff, 1<<21
// guard, monotonic flags, separate head kernel.

#define B_    128
#define T_    1024
#define IN_   256
#define H_    512
#define NG    8
#define WPG   32
#define SGRP  16
#define JT    16
#define NT    512
#define RWU   776                          // U row pitch (bf16 elems); *2B = 1552
#define U_HI_OFF   0
#define U_LO_OFF   (SGRP*RWU*2)            // 24,832
#define WLO_OFF    (2*SGRP*RWU*2)          // 49,664
#define ACC_OFF    (WLO_OFF + 8*9*64*16)   // 123,392
#define LDS_DYN    (ACC_OFF + 4*16*17*4)   // 127,744 B

typedef __attribute__((ext_vector_type(8))) short bf16x8;
typedef __attribute__((ext_vector_type(4))) float f32x4;

#define MFMA(a,b,c) __builtin_amdgcn_mfma_f32_16x16x32_bf16((a),(b),(c),0,0,0)

__device__ __forceinline__ float sig_(float v){ return 1.0f/(1.0f + __expf(-v)); }
__device__ __forceinline__ float tanh_(float v){
  float e = __expf(2.0f*v);
  return 1.0f - 2.0f/(e + 1.0f);
}
__device__ __forceinline__ unsigned short bf16rn(float f){
  unsigned u = __float_as_uint(f);
  return (unsigned short)((u + 0x7FFFu + ((u>>16)&1u)) >> 16);
}

// IF-coherent ops (sc0 sc1). Data operands <=64-bit except 128-bit OUTPUTS.
#define CLOADU4(dst, p) asm volatile("global_load_dwordx4 %0, %1, off sc0 sc1" : "=v"(dst) : "v"(p) : "memory")
#define CLOADI(dst, p)  asm volatile("global_load_dword %0, %1, off sc0 sc1"   : "=v"(dst) : "v"(p) : "memory")
#define CSTOREU(p, v)   asm volatile("global_store_dword %0, %1, off sc0 sc1"  :: "v"(p), "v"(v) : "memory")
#define VWAIT0()        do{ asm volatile("s_waitcnt vmcnt(0)" ::: "memory"); __builtin_amdgcn_sched_barrier(0); }while(0)

__device__ __forceinline__ int poll_group(const int* fbase, int lane, int target){
  const int* fp = fbase + (lane & 31);
  int guard = 0;
  for (;;){
    int fv;
    CLOADI(fv, fp);
    asm volatile("s_waitcnt vmcnt(0)" ::: "memory");
    if (__all(fv >= target)) return 0;
    __builtin_amdgcn_s_sleep(4);
    if (++guard > (1<<21)) return 1;
  }
}

__global__ void __launch_bounds__(NT, 2)
rnn_persist(const float* __restrict__ x, const float* __restrict__ W_ih,
            const float* __restrict__ W_hh, const float* __restrict__ bias,
            const float* __restrict__ bias_n, unsigned* __restrict__ h_buf,
            int* __restrict__ flags)
{
  extern __shared__ char lds[];
  unsigned short* Uhi = (unsigned short*)(lds + U_HI_OFF);
  unsigned short* Ulo = (unsigned short*)(lds + U_LO_OFF);
  char*  Wlo  = lds + WLO_OFF;
  float* accb = (float*)(lds + ACC_OFF);

  const int bid = (int)blockIdx.x;
  const int g   = bid & (NG-1);
  const int w   = bid >> 3;
  const int tid = (int)threadIdx.x;
  const int w8  = tid >> 6;            // wave [0,8)
  const int l   = tid & 63;            // lane
  const int jl  = l & 15;              // frag row/col lane index
  const int kq  = l >> 4;              // k-quarter [0,4)
  const int b0  = g*SGRP;
  const int jg_l = w*JT + jl;

  // ---- init: A-fragments. hi -> 36 VGPRs; lo -> LDS (frag-order) ----
  bf16x8 ahi[9];
#pragma unroll
  for (int ci=0; ci<3; ci++){
    const int c = 3*w8 + ci;
#pragma unroll
    for (int gi=0; gi<3; gi++){
      const int f = 3*ci + gi;
      const int grow = ((gi==2) ? 2*H_ : gi*H_) + jg_l;
      const float* p = (c < 8)
        ? (W_ih + (size_t)grow*IN_ + (32*c + 8*kq))
        : (W_hh + (size_t)grow*H_  + (32*c - 256 + 8*kq));
      const float4 v0 = *(const float4*)p;
      const float4 v1 = *(const float4*)(p+4);
      const float vv[8] = {v0.x,v0.y,v0.z,v0.w,v1.x,v1.y,v1.z,v1.w};
      bf16x8 hi8, lo8;
#pragma unroll
      for (int i=0;i<8;i++){
        const unsigned short h = bf16rn(vv[i]);
        const float fh = __uint_as_float(((unsigned)h)<<16);
        hi8[i] = (short)h;
        lo8[i] = (short)bf16rn(vv[i]-fh);
      }
      ahi[f] = hi8;
      *(bf16x8*)(Wlo + ((size_t)(w8*9 + f)*64 + l)*16) = lo8;
    }
  }
  // biases for gate threads (j = tid&15)
  float br, bz, bni, bnh;
  { const int jj = w*JT + (tid & 15);
    br = bias[jj]; bz = bias[H_+jj]; bni = bias[2*H_+jj]; bnh = bias_n[jj]; }
  __syncthreads();                     // Wlo visible

  unsigned* const hb0 = h_buf;
  unsigned* const hb1 = h_buf + (size_t)B_*H_;
  int dead = 0;

  for (int t=0; t<T_; ++t){
    const unsigned* hc = (t & 1) ? hb1 : hb0;
    unsigned*      hnx = (t & 1) ? hb0 : hb1;

    // ---- zero acc buffer (prev gate phase ended at barrier D) ----
    for (int i=tid; i<4*16*17; i+=NT) accb[i] = 0.f;

    // ---- x-stage (flag-independent): fp32 -> bf16 hi/lo -> U[0:256) ----
    {
      const int ss = tid>>5, c2 = tid&31;
      const float* xp = x + ((size_t)(b0+ss)*T_ + (size_t)t)*IN_ + c2*8;
      const float4 a = *(const float4*)xp;
      const float4 b = *(const float4*)(xp+4);
      const float vv[8] = {a.x,a.y,a.z,a.w,b.x,b.y,b.z,b.w};
      unsigned hw[4], lw[4];
#pragma unroll
      for (int q=0;q<4;q++){
        const unsigned short h0 = bf16rn(vv[2*q]);
        const unsigned short h1 = bf16rn(vv[2*q+1]);
        const float f0 = __uint_as_float(((unsigned)h0)<<16);
        const float f1 = __uint_as_float(((unsigned)h1)<<16);
        const unsigned short l0 = bf16rn(vv[2*q]-f0);
        const unsigned short l1 = bf16rn(vv[2*q+1]-f1);
        hw[q] = (unsigned)h0 | ((unsigned)h1<<16);
        lw[q] = (unsigned)l0 | ((unsigned)l1<<16);
      }
      *(uint4*)((char*)Uhi + ss*1552 + c2*16) = make_uint4(hw[0],hw[1],hw[2],hw[3]);
      *(uint4*)((char*)Ulo + ss*1552 + c2*16) = make_uint4(lw[0],lw[1],lw[2],lw[3]);
    }

    // ---- wave0 polls for h^t; others wait at barrier P ----
    if (tid < 64 && t > 0 && !dead) dead = poll_group(flags + g*WPG, l, t);
    __syncthreads();                   // P

    // ---- h-stage: packed u32 -> split hi/lo -> U[256:768) ----
    {
      const int ss = tid>>5, c2 = tid&31;
      const unsigned* hp = hc + (size_t)(b0+ss)*H_ + c2*16;
      uint4 p0,p1,p2,p3;
      CLOADU4(p0, hp); CLOADU4(p1, hp+4); CLOADU4(p2, hp+8); CLOADU4(p3, hp+12);
      VWAIT0();
      const unsigned P[16] = {p0.x,p0.y,p0.z,p0.w, p1.x,p1.y,p1.z,p1.w,
                              p2.x,p2.y,p2.z,p2.w, p3.x,p3.y,p3.z,p3.w};
      unsigned hwv[8], lwv[8];
#pragma unroll
      for (int q=0;q<8;q++){
        hwv[q] = (P[2*q]>>16) | (P[2*q+1] & 0xFFFF0000u);
        lwv[q] = (P[2*q] & 0xFFFFu) | (P[2*q+1]<<16);
      }
      char* dh = (char*)Uhi + ss*1552 + 512 + c2*32;
      char* dl = (char*)Ulo + ss*1552 + 512 + c2*32;
      *(uint4*)dh      = make_uint4(hwv[0],hwv[1],hwv[2],hwv[3]);
      *(uint4*)(dh+16) = make_uint4(hwv[4],hwv[5],hwv[6],hwv[7]);
      *(uint4*)dl      = make_uint4(lwv[0],lwv[1],lwv[2],lwv[3]);
      *(uint4*)(dl+16) = make_uint4(lwv[4],lwv[5],lwv[6],lwv[7]);
    }
    __syncthreads();                   // B: U complete

    // ---- MFMA: 3 chunks x {r,z,ni|nh} x 3 passes ----
    f32x4 cR = {0,0,0,0}, cZ = {0,0,0,0}, cNI = {0,0,0,0}, cNH = {0,0,0,0};
#pragma unroll
    for (int ci=0; ci<3; ci++){
      const int c = 3*w8 + ci;
      const bf16x8 bhi = *(const bf16x8*)((char*)Uhi + jl*1552 + 64*c + 16*kq);
      const bf16x8 blo = *(const bf16x8*)((char*)Ulo + jl*1552 + 64*c + 16*kq);
      const bf16x8 aloR = *(const bf16x8*)(Wlo + ((size_t)(w8*9+3*ci+0)*64 + l)*16);
      const bf16x8 aloZ = *(const bf16x8*)(Wlo + ((size_t)(w8*9+3*ci+1)*64 + l)*16);
      const bf16x8 aloN = *(const bf16x8*)(Wlo + ((size_t)(w8*9+3*ci+2)*64 + l)*16);
      cR = MFMA(ahi[3*ci+0], bhi, cR);
      cR = MFMA(ahi[3*ci+0], blo, cR);
      cR = MFMA(aloR,        bhi, cR);
      cZ = MFMA(ahi[3*ci+1], bhi, cZ);
      cZ = MFMA(ahi[3*ci+1], blo, cZ);
      cZ = MFMA(aloZ,        bhi, cZ);
      if (c < 8){
        cNI = MFMA(ahi[3*ci+2], bhi, cNI);
        cNI = MFMA(ahi[3*ci+2], blo, cNI);
        cNI = MFMA(aloN,        bhi, cNI);
      } else {
        cNH = MFMA(ahi[3*ci+2], bhi, cNH);
        cNH = MFMA(ahi[3*ci+2], blo, cNH);
        cNH = MFMA(aloN,        bhi, cNH);
      }
    }
    // ---- cross-wave combine: ds_add_f32 into accb[4][16][17] ----
    {
      const int base = (kq*4)*17 + jl;
#pragma unroll
      for (int i=0;i<4;i++){
        atomicAdd(&accb[0*272 + base + i*17], cR[i]);
        atomicAdd(&accb[1*272 + base + i*17], cZ[i]);
      }
      if (w8 <= 2){
#pragma unroll
        for (int i=0;i<4;i++) atomicAdd(&accb[2*272 + base + i*17], cNI[i]);
      }
      if (w8 >= 2){
#pragma unroll
        for (int i=0;i<4;i++) atomicAdd(&accb[3*272 + base + i*17], cNH[i]);
      }
    }
    __syncthreads();                   // C: sums complete

    // ---- gates (256 threads): s = tid>>4, j = tid&15 ----
    if (tid < 256){
      const int s = tid>>4, j = tid&15;
      const float SR  = accb[0*272 + j*17 + s];
      const float SZ  = accb[1*272 + j*17 + s];
      const float SNI = accb[2*272 + j*17 + s];
      const float SNH = accb[3*272 + j*17 + s];
      const int hidx = 256 + w*JT + j;
      const float hold = __uint_as_float(((unsigned)Uhi[s*RWU + hidx])<<16)
                       + __uint_as_float(((unsigned)Ulo[s*RWU + hidx])<<16);
      const float r = sig_(SR + br);
      const float z = sig_(SZ + bz);
      const float n = tanh_(SNI + bni + r*(SNH + bnh));
      const float hnew = (1.0f - z)*n + z*hold;
      const unsigned short hh = bf16rn(hnew);
      const float fh = __uint_as_float(((unsigned)hh)<<16);
      const unsigned short ll2 = bf16rn(hnew - fh);
      const unsigned packed = (((unsigned)hh)<<16) | (unsigned)ll2;
      CSTOREU(hnx + (size_t)(b0+s)*H_ + w*JT + j, packed);
    }
    asm volatile("s_waitcnt vmcnt(0)" ::: "memory");
    __syncthreads();                   // D: all hnew stores drained
    if (tid == 0){
      int* fp = &flags[g*WPG + w];
      const int fv = t + 1;
      CSTOREU(fp, fv);
    }
  }
}

__global__ void head_k(const unsigned* __restrict__ h, const float* __restrict__ W_out,
                       const float* __restrict__ b_out, float* __restrict__ out)
{
  const int b = (int)blockIdx.x;       // 128 blocks, one sample each
  const int l = (int)threadIdx.x;      // 64 lanes
  const unsigned* hp = h + (size_t)b*H_ + l*8;
  const float* wp = W_out + l*8;
  float a = 0.f;
#pragma unroll
  for (int q=0;q<8;q++){
    const unsigned p = hp[q];
    const float v = __uint_as_float(p & 0xFFFF0000u) + __uint_as_float(p << 16);
    a = fmaf(v, wp[q], a);
  }
#pragma unroll
  for (int m=1;m<64;m<<=1) a += __shfl_xor(a, m, 64);
  if (l == 0) out[b] = sig_(a + b_out[0]);
}

extern "C" void kernel_launch(void* const* d_in, const int* in_sizes, int n_in,
                              void* d_out, int out_size, void* d_ws, size_t ws_size,
                              hipStream_t stream)
{
  const float* x    = (const float*)d_in[0];
  const float* Wih  = (const float*)d_in[1];
  const float* Whh  = (const float*)d_in[2];
  const float* bias = (const float*)d_in[3];
  const float* bn   = (const float*)d_in[4];
  const float* Wout = (const float*)d_in[5];
  const float* bout = (const float*)d_in[6];
  float* out      = (float*)d_out;
  unsigned* h_buf = (unsigned*)d_ws;                                     // 512 KB (2 bufs)
  int* flags      = (int*)((char*)d_ws + (size_t)2*B_*H_*sizeof(unsigned));

  // zero h0 (packed 0 == 0.0f) + flags every launch
  (void)hipMemsetAsync(d_ws, 0, (size_t)2*B_*H_*sizeof(unsigned) + 4096, stream);

  (void)hipFuncSetAttribute((const void*)rnn_persist,
                            hipFuncAttributeMaxDynamicSharedMemorySize, LDS_DYN);

  void* args[7];
  args[0]=(void*)&x;    args[1]=(void*)&Wih;  args[2]=(void*)&Whh; args[3]=(void*)&bias;
  args[4]=(void*)&bn;   args[5]=(void*)&h_buf; args[6]=(void*)&flags;
  hipError_t e = hipLaunchCooperativeKernel((const void*)rnn_persist,
                                            dim3(256), dim3(NT), args, LDS_DYN, stream);
  if (e != hipSuccess){
    (void)hipGetLastError();
    rnn_persist<<<dim3(256), dim3(NT), LDS_DYN, stream>>>(x, Wih, Whh, bias, bn, h_buf, flags);
  }
  // T_ even -> final h in hb0; kernel boundary makes h_buf coherent for head_k
  head_k<<<dim3(128), dim3(64), 0, stream>>>(h_buf, Wout, bout, out);
}

// Round 14
// 11833.810 us; speedup vs baseline: 1.3062x; 1.0004x over previous
//
#include <hip/hip_runtime.h>

// GRU  B=128, T=1024, IN=256, H=512, OUT=1  (all fp32)
//
// v13: split-bf16 MFMA. fp32 = bf16hi + bf16lo; W.u ~ Whi.uhi + Whi.ulo +
// Wlo.uhi (3 passes; dropped lo.lo ~ 3e-7 per dot). Virtual operand U[k],
// K=768 = x(256) ++ h(512), staged per step into LDS as bf16 hi/lo (row
// pitch 776). 4 gate row-sets: r,z (K=768), ni (x-only), nh (h-only).
// Per wg (512 thr, 8 waves): wave w8 owns K-chunks {3w8..3w8+2} (32-K each);
// 27 x mfma_f32_16x16x32_bf16 per wave per step. A=W frags: hi in 36 VGPRs
// (fits proven 128 budget), lo pre-swizzled in LDS. Layouts: A row=lane&15,
// k=8*(lane>>4)+i; B col=lane&15 same k; C/D col=lane&15 row=4*(lane>>4)+i
// (m89-verified). Cross-wave combine: ds_add_f32 into [4][16][17] LDS buf.
// Gate phase: 256 thr -> hnew packed (hi<<16|lo) u32 -> coalesced store.
// Sync = v12-proven: wave0-only sc0/sc1 flag poll, s_sleep backoff, 1<<21
// guard, monotonic flags, separate head kernel.

#define B_    128
#define T_    1024
#define IN_   256
#define H_    512
#define NG    8
#define WPG   32
#define SGRP  16
#define JT    16
#define NT    512
#define RWU   776                          // U row pitch (bf16 elems); *2B = 1552
#define U_HI_OFF   0
#define U_LO_OFF   (SGRP*RWU*2)            // 24,832
#define WLO_OFF    (2*SGRP*RWU*2)          // 49,664
#define ACC_OFF    (WLO_OFF + 8*9*64*16)   // 123,392
#define LDS_DYN    (ACC_OFF + 4*16*17*4)   // 127,744 B

typedef __attribute__((ext_vector_type(8))) short bf16x8;
typedef __attribute__((ext_vector_type(4))) float f32x4;

#define MFMA(a,b,c) __builtin_amdgcn_mfma_f32_16x16x32_bf16((a),(b),(c),0,0,0)

__device__ __forceinline__ float sig_(float v){ return 1.0f/(1.0f + __expf(-v)); }
__device__ __forceinline__ float tanh_(float v){
  float e = __expf(2.0f*v);
  return 1.0f - 2.0f/(e + 1.0f);
}
__device__ __forceinline__ unsigned short bf16rn(float f){
  unsigned u = __float_as_uint(f);
  return (unsigned short)((u + 0x7FFFu + ((u>>16)&1u)) >> 16);
}

// IF-coherent ops (sc0 sc1). Data operands <=64-bit except 128-bit OUTPUTS.
#define CLOADU4(dst, p) asm volatile("global_load_dwordx4 %0, %1, off sc0 sc1" : "=v"(dst) : "v"(p) : "memory")
#define CLOADI(dst, p)  asm volatile("global_load_dword %0, %1, off sc0 sc1"   : "=v"(dst) : "v"(p) : "memory")
#define CSTOREU(p, v)   asm volatile("global_store_dword %0, %1, off sc0 sc1"  :: "v"(p), "v"(v) : "memory")
#define VWAIT0()        do{ asm volatile("s_waitcnt vmcnt(0)" ::: "memory"); __builtin_amdgcn_sched_barrier(0); }while(0)

__device__ __forceinline__ int poll_group(const int* fbase, int lane, int target){
  const int* fp = fbase + (lane & 31);
  int guard = 0;
  for (;;){
    int fv;
    CLOADI(fv, fp);
    asm volatile("s_waitcnt vmcnt(0)" ::: "memory");
    if (__all(fv >= target)) return 0;
    __builtin_amdgcn_s_sleep(4);
    if (++guard > (1<<21)) return 1;
  }
}

__global__ void __launch_bounds__(NT, 2)
rnn_persist(const float* __restrict__ x, const float* __restrict__ W_ih,
            const float* __restrict__ W_hh, const float* __restrict__ bias,
            const float* __restrict__ bias_n, unsigned* __restrict__ h_buf,
            int* __restrict__ flags)
{
  extern __shared__ char lds[];
  unsigned short* Uhi = (unsigned short*)(lds + U_HI_OFF);
  unsigned short* Ulo = (unsigned short*)(lds + U_LO_OFF);
  char*  Wlo  = lds + WLO_OFF;
  float* accb = (float*)(lds + ACC_OFF);

  const int bid = (int)blockIdx.x;
  const int g   = bid & (NG-1);
  const int w   = bid >> 3;
  const int tid = (int)threadIdx.x;
  const int w8  = tid >> 6;            // wave [0,8)
  const int l   = tid & 63;            // lane
  const int jl  = l & 15;              // frag row/col lane index
  const int kq  = l >> 4;              // k-quarter [0,4)
  const int b0  = g*SGRP;
  const int jg_l = w*JT + jl;

  // ---- init: A-fragments. hi -> 36 VGPRs; lo -> LDS (frag-order) ----
  bf16x8 ahi[9];
#pragma unroll
  for (int ci=0; ci<3; ci++){
    const int c = 3*w8 + ci;
#pragma unroll
    for (int gi=0; gi<3; gi++){
      const int f = 3*ci + gi;
      const int grow = ((gi==2) ? 2*H_ : gi*H_) + jg_l;
      const float* p = (c < 8)
        ? (W_ih + (size_t)grow*IN_ + (32*c + 8*kq))
        : (W_hh + (size_t)grow*H_  + (32*c - 256 + 8*kq));
      const float4 v0 = *(const float4*)p;
      const float4 v1 = *(const float4*)(p+4);
      const float vv[8] = {v0.x,v0.y,v0.z,v0.w,v1.x,v1.y,v1.z,v1.w};
      bf16x8 hi8, lo8;
#pragma unroll
      for (int i=0;i<8;i++){
        const unsigned short h = bf16rn(vv[i]);
        const float fh = __uint_as_float(((unsigned)h)<<16);
        hi8[i] = (short)h;
        lo8[i] = (short)bf16rn(vv[i]-fh);
      }
      ahi[f] = hi8;
      *(bf16x8*)(Wlo + ((size_t)(w8*9 + f)*64 + l)*16) = lo8;
    }
  }
  // biases for gate threads (j = tid&15)
  float br, bz, bni, bnh;
  { const int jj = w*JT + (tid & 15);
    br = bias[jj]; bz = bias[H_+jj]; bni = bias[2*H_+jj]; bnh = bias_n[jj]; }
  __syncthreads();                     // Wlo visible

  unsigned* const hb0 = h_buf;
  unsigned* const hb1 = h_buf + (size_t)B_*H_;
  int dead = 0;

  for (int t=0; t<T_; ++t){
    const unsigned* hc = (t & 1) ? hb1 : hb0;
    unsigned*      hnx = (t & 1) ? hb0 : hb1;

    // ---- zero acc buffer (prev gate phase ended at barrier D) ----
    for (int i=tid; i<4*16*17; i+=NT) accb[i] = 0.f;

    // ---- x-stage (flag-independent): fp32 -> bf16 hi/lo -> U[0:256) ----
    {
      const int ss = tid>>5, c2 = tid&31;
      const float* xp = x + ((size_t)(b0+ss)*T_ + (size_t)t)*IN_ + c2*8;
      const float4 a = *(const float4*)xp;
      const float4 b = *(const float4*)(xp+4);
      const float vv[8] = {a.x,a.y,a.z,a.w,b.x,b.y,b.z,b.w};
      unsigned hw[4], lw[4];
#pragma unroll
      for (int q=0;q<4;q++){
        const unsigned short h0 = bf16rn(vv[2*q]);
        const unsigned short h1 = bf16rn(vv[2*q+1]);
        const float f0 = __uint_as_float(((unsigned)h0)<<16);
        const float f1 = __uint_as_float(((unsigned)h1)<<16);
        const unsigned short l0 = bf16rn(vv[2*q]-f0);
        const unsigned short l1 = bf16rn(vv[2*q+1]-f1);
        hw[q] = (unsigned)h0 | ((unsigned)h1<<16);
        lw[q] = (unsigned)l0 | ((unsigned)l1<<16);
      }
      *(uint4*)((char*)Uhi + ss*1552 + c2*16) = make_uint4(hw[0],hw[1],hw[2],hw[3]);
      *(uint4*)((char*)Ulo + ss*1552 + c2*16) = make_uint4(lw[0],lw[1],lw[2],lw[3]);
    }

    // ---- wave0 polls for h^t; others wait at barrier P ----
    if (tid < 64 && t > 0 && !dead) dead = poll_group(flags + g*WPG, l, t);
    __syncthreads();                   // P

    // ---- h-stage: packed u32 -> split hi/lo -> U[256:768) ----
    {
      const int ss = tid>>5, c2 = tid&31;
      const unsigned* hp = hc + (size_t)(b0+ss)*H_ + c2*16;
      uint4 p0,p1,p2,p3;
      CLOADU4(p0, hp); CLOADU4(p1, hp+4); CLOADU4(p2, hp+8); CLOADU4(p3, hp+12);
      VWAIT0();
      const unsigned P[16] = {p0.x,p0.y,p0.z,p0.w, p1.x,p1.y,p1.z,p1.w,
                              p2.x,p2.y,p2.z,p2.w, p3.x,p3.y,p3.z,p3.w};
      unsigned hwv[8], lwv[8];
#pragma unroll
      for (int q=0;q<8;q++){
        hwv[q] = (P[2*q]>>16) | (P[2*q+1] & 0xFFFF0000u);
        lwv[q] = (P[2*q] & 0xFFFFu) | (P[2*q+1]<<16);
      }
      char* dh = (char*)Uhi + ss*1552 + 512 + c2*32;
      char* dl = (char*)Ulo + ss*1552 + 512 + c2*32;
      *(uint4*)dh      = make_uint4(hwv[0],hwv[1],hwv[2],hwv[3]);
      *(uint4*)(dh+16) = make_uint4(hwv[4],hwv[5],hwv[6],hwv[7]);
      *(uint4*)dl      = make_uint4(lwv[0],lwv[1],lwv[2],lwv[3]);
      *(uint4*)(dl+16) = make_uint4(lwv[4],lwv[5],lwv[6],lwv[7]);
    }
    __syncthreads();                   // B: U complete

    // ---- MFMA: 3 chunks x {r,z,ni|nh} x 3 passes ----
    f32x4 cR = {0,0,0,0}, cZ = {0,0,0,0}, cNI = {0,0,0,0}, cNH = {0,0,0,0};
#pragma unroll
    for (int ci=0; ci<3; ci++){
      const int c = 3*w8 + ci;
      const bf16x8 bhi = *(const bf16x8*)((char*)Uhi + jl*1552 + 64*c + 16*kq);
      const bf16x8 blo = *(const bf16x8*)((char*)Ulo + jl*1552 + 64*c + 16*kq);
      const bf16x8 aloR = *(const bf16x8*)(Wlo + ((size_t)(w8*9+3*ci+0)*64 + l)*16);
      const bf16x8 aloZ = *(const bf16x8*)(Wlo + ((size_t)(w8*9+3*ci+1)*64 + l)*16);
      const bf16x8 aloN = *(const bf16x8*)(Wlo + ((size_t)(w8*9+3*ci+2)*64 + l)*16);
      cR = MFMA(ahi[3*ci+0], bhi, cR);
      cR = MFMA(ahi[3*ci+0], blo, cR);
      cR = MFMA(aloR,        bhi, cR);
      cZ = MFMA(ahi[3*ci+1], bhi, cZ);
      cZ = MFMA(ahi[3*ci+1], blo, cZ);
      cZ = MFMA(aloZ,        bhi, cZ);
      if (c < 8){
        cNI = MFMA(ahi[3*ci+2], bhi, cNI);
        cNI = MFMA(ahi[3*ci+2], blo, cNI);
        cNI = MFMA(aloN,        bhi, cNI);
      } else {
        cNH = MFMA(ahi[3*ci+2], bhi, cNH);
        cNH = MFMA(ahi[3*ci+2], blo, cNH);
        cNH = MFMA(aloN,        bhi, cNH);
      }
    }
    // ---- cross-wave combine: ds_add_f32 into accb[4][16][17] ----
    {
      const int base = (kq*4)*17 + jl;
#pragma unroll
      for (int i=0;i<4;i++){
        atomicAdd(&accb[0*272 + base + i*17], cR[i]);
        atomicAdd(&accb[1*272 + base + i*17], cZ[i]);
      }
      if (w8 <= 2){
#pragma unroll
        for (int i=0;i<4;i++) atomicAdd(&accb[2*272 + base + i*17], cNI[i]);
      }
      if (w8 >= 2){
#pragma unroll
        for (int i=0;i<4;i++) atomicAdd(&accb[3*272 + base + i*17], cNH[i]);
      }
    }
    __syncthreads();                   // C: sums complete

    // ---- gates (256 threads): s = tid>>4, j = tid&15 ----
    if (tid < 256){
      const int s = tid>>4, j = tid&15;
      const float SR  = accb[0*272 + j*17 + s];
      const float SZ  = accb[1*272 + j*17 + s];
      const float SNI = accb[2*272 + j*17 + s];
      const float SNH = accb[3*272 + j*17 + s];
      const int hidx = 256 + w*JT + j;
      const float hold = __uint_as_float(((unsigned)Uhi[s*RWU + hidx])<<16)
                       + __uint_as_float(((unsigned)Ulo[s*RWU + hidx])<<16);
      const float r = sig_(SR + br);
      const float z = sig_(SZ + bz);
      const float n = tanh_(SNI + bni + r*(SNH + bnh));
      const float hnew = (1.0f - z)*n + z*hold;
      const unsigned short hh = bf16rn(hnew);
      const float fh = __uint_as_float(((unsigned)hh)<<16);
      const unsigned short ll2 = bf16rn(hnew - fh);
      const unsigned packed = (((unsigned)hh)<<16) | (unsigned)ll2;
      CSTOREU(hnx + (size_t)(b0+s)*H_ + w*JT + j, packed);
    }
    asm volatile("s_waitcnt vmcnt(0)" ::: "memory");
    __syncthreads();                   // D: all hnew stores drained
    if (tid == 0){
      int* fp = &flags[g*WPG + w];
      const int fv = t + 1;
      CSTOREU(fp, fv);
    }
  }
}

__global__ void head_k(const unsigned* __restrict__ h, const float* __restrict__ W_out,
                       const float* __restrict__ b_out, float* __restrict__ out)
{
  const int b = (int)blockIdx.x;       // 128 blocks, one sample each
  const int l = (int)threadIdx.x;      // 64 lanes
  const unsigned* hp = h + (size_t)b*H_ + l*8;
  const float* wp = W_out + l*8;
  float a = 0.f;
#pragma unroll
  for (int q=0;q<8;q++){
    const unsigned p = hp[q];
    const float v = __uint_as_float(p & 0xFFFF0000u) + __uint_as_float(p << 16);
    a = fmaf(v, wp[q], a);
  }
#pragma unroll
  for (int m=1;m<64;m<<=1) a += __shfl_xor(a, m, 64);
  if (l == 0) out[b] = sig_(a + b_out[0]);
}

extern "C" void kernel_launch(void* const* d_in, const int* in_sizes, int n_in,
                              void* d_out, int out_size, void* d_ws, size_t ws_size,
                              hipStream_t stream)
{
  const float* x    = (const float*)d_in[0];
  const float* Wih  = (const float*)d_in[1];
  const float* Whh  = (const float*)d_in[2];
  const float* bias = (const float*)d_in[3];
  const float* bn   = (const float*)d_in[4];
  const float* Wout = (const float*)d_in[5];
  const float* bout = (const float*)d_in[6];
  float* out      = (float*)d_out;
  unsigned* h_buf = (unsigned*)d_ws;                                     // 512 KB (2 bufs)
  int* flags      = (int*)((char*)d_ws + (size_t)2*B_*H_*sizeof(unsigned));

  // zero h0 (packed 0 == 0.0f) + flags every launch
  (void)hipMemsetAsync(d_ws, 0, (size_t)2*B_*H_*sizeof(unsigned) + 4096, stream);

  (void)hipFuncSetAttribute((const void*)rnn_persist,
                            hipFuncAttributeMaxDynamicSharedMemorySize, LDS_DYN);

  void* args[7];
  args[0]=(void*)&x;    args[1]=(void*)&Wih;  args[2]=(void*)&Whh; args[3]=(void*)&bias;
  args[4]=(void*)&bn;   args[5]=(void*)&h_buf; args[6]=(void*)&flags;
  hipError_t e = hipLaunchCooperativeKernel((const void*)rnn_persist,
                                            dim3(256), dim3(NT), args, LDS_DYN, stream);
  if (e != hipSuccess){
    (void)hipGetLastError();
    rnn_persist<<<dim3(256), dim3(NT), LDS_DYN, stream>>>(x, Wih, Whh, bias, bn, h_buf, flags);
  }
  // T_ even -> final h in hb0; kernel boundary makes h_buf coherent for head_k
  head_k<<<dim3(128), dim3(64), 0, stream>>>(h_buf, Wout, bout, out);
}